// Round 1
// baseline (179.780 us; speedup 1.0000x reference)
//
#include <hip/hip_runtime.h>
#include <math.h>

#define Tt 4096
#define Cc 1024
#define Hh 64

typedef __attribute__((ext_vector_type(8))) short bf16x8;
typedef __attribute__((ext_vector_type(4))) float f32x4;
typedef unsigned int u32;

__device__ inline unsigned short f2bf(float f) {
    unsigned u = __float_as_uint(f);
    u = (u + 0x7FFFu + ((u >> 16) & 1u)) >> 16;   // RNE
    return (unsigned short)u;
}

// ---------- W^T bf16 [192][1024]; kScale folded into Wq ----------
__global__ __launch_bounds__(256) void wt_build(
    const float* __restrict__ Wq, const float* __restrict__ Wk,
    const float* __restrict__ Wv, unsigned short* __restrict__ Wt)
{
    int e = blockIdx.x * 256 + threadIdx.x;   // 0..196607
    int k = e & 1023, n = e >> 10;
    float v;
    if (n < 64)       v = Wq[k * 64 + n] * 0.03125f;   // fold 1024^-0.5 into Q
    else if (n < 128) v = Wk[k * 64 + (n - 64)];
    else              v = Wv[k * 64 + (n - 128)];
    Wt[n * 1024 + k] = f2bf(v);
}

// ---------- QKV GEMM v2: latency-oriented re-tile ----------
// 1024 blocks x 4 waves (16 waves/CU). Block tile 16M x 192N, BK=64.
// A: tiny double-buffered LDS (shared by all 4 waves), raw s_barrier +
//    lgkmcnt(0) only (global loads never drained at the barrier).
// B: direct global->reg bf16x8 fragments (W^T is 384 KB, L2-resident),
//    software-pipelined one step ahead.
#define LDAQ 72   // A row stride in shorts: 144 B, conflict-free for b128 frag reads
__global__ __launch_bounds__(256, 4) void qkv_gemm(
    const float* __restrict__ x, const unsigned short* __restrict__ wt,
    unsigned short* __restrict__ qb, unsigned short* __restrict__ kb,
    unsigned short* __restrict__ vt)
{
    __shared__ unsigned short as_[2 * 16 * LDAQ];   // 4608 B

    const int t = threadIdx.x, w = t >> 6, lane = t & 63;
    const int col = lane & 15, quad = lane >> 4;
    const long rowbase = (long)blockIdx.x * 16;

    // A staging role: thread t loads row arow, 16B segment aseg (16x64 fp32 / step)
    const int arow = t >> 4, aseg = t & 15;
    const float* xrow = x + (rowbase + arow) * Cc + aseg * 4;
    // B fragment base for this lane: row n = w*48 + col, k-offset quad*8
    const unsigned short* wbase = wt + (w * 48 + col) * 1024 + quad * 8;

    f32x4 acc[3];
#pragma unroll
    for (int nt = 0; nt < 3; ++nt) acc[nt] = (f32x4){0.f, 0.f, 0.f, 0.f};

    bf16x8 bcur[3][2], bnxt[3][2];

    // ---- prologue: B frags for step 0 (in flight), stage A step 0
#pragma unroll
    for (int nt = 0; nt < 3; ++nt)
#pragma unroll
        for (int kc = 0; kc < 2; ++kc)
            bcur[nt][kc] = *(const bf16x8*)(wbase + nt * 16384 + kc * 32);
    {
        float4 v = *(const float4*)xrow;
        ushort4 pk = { f2bf(v.x), f2bf(v.y), f2bf(v.z), f2bf(v.w) };
        *(ushort4*)&as_[arow * LDAQ + aseg * 4] = pk;
    }
    asm volatile("s_waitcnt lgkmcnt(0)" ::: "memory");
    __builtin_amdgcn_s_barrier();

#pragma unroll
    for (int kk = 0; kk < Cc; kk += 64) {
        const int cur = (kk >> 6) & 1, nxt = cur ^ 1;
        const bool hasnext = (kk + 64) < Cc;
        float4 ar;
        if (hasnext) {
            // issue next-step loads immediately after the barrier; they
            // complete under this step's MFMAs (no vmcnt drain anywhere)
            ar = *(const float4*)(xrow + kk + 64);
#pragma unroll
            for (int nt = 0; nt < 3; ++nt)
#pragma unroll
                for (int kc = 0; kc < 2; ++kc)
                    bnxt[nt][kc] = *(const bf16x8*)(wbase + nt * 16384 + kk + 64 + kc * 32);
        }
        // ---- compute on buf[cur]
        bf16x8 af[2];
#pragma unroll
        for (int kc = 0; kc < 2; ++kc)
            af[kc] = *(const bf16x8*)&as_[cur * (16 * LDAQ) + col * LDAQ + kc * 32 + quad * 8];
#pragma unroll
        for (int nt = 0; nt < 3; ++nt) {
            acc[nt] = __builtin_amdgcn_mfma_f32_16x16x32_bf16(af[0], bcur[nt][0], acc[nt], 0, 0, 0);
            acc[nt] = __builtin_amdgcn_mfma_f32_16x16x32_bf16(af[1], bcur[nt][1], acc[nt], 0, 0, 0);
        }
        if (hasnext) {
            ushort4 pk = { f2bf(ar.x), f2bf(ar.y), f2bf(ar.z), f2bf(ar.w) };
            *(ushort4*)&as_[nxt * (16 * LDAQ) + arow * LDAQ + aseg * 4] = pk;
            asm volatile("s_waitcnt lgkmcnt(0)" ::: "memory");
            __builtin_amdgcn_s_barrier();
#pragma unroll
            for (int nt = 0; nt < 3; ++nt)
#pragma unroll
                for (int kc = 0; kc < 2; ++kc)
                    bcur[nt][kc] = bnxt[nt][kc];
        }
    }

    // ---- epilogue: wave w owns n-tiles ntg = 3w..3w+2
    const long b = rowbase >> 12;
    const int tloc0 = (int)(rowbase & 4095) + quad * 4;
#pragma unroll
    for (int nt = 0; nt < 3; ++nt) {
        int ntg = w * 3 + nt;
        int n = ntg * 16 + col;
        if (ntg < 4) {
#pragma unroll
            for (int reg = 0; reg < 4; ++reg)
                qb[(rowbase + quad * 4 + reg) * Hh + n] = f2bf(acc[nt][reg]);
        } else if (ntg < 8) {
#pragma unroll
            for (int reg = 0; reg < 4; ++reg)
                kb[(rowbase + quad * 4 + reg) * Hh + (n - 64)] = f2bf(acc[nt][reg]);
        } else {
            int h = n - 128;
            ushort4 pk = { f2bf(acc[nt][0]), f2bf(acc[nt][1]),
                           f2bf(acc[nt][2]), f2bf(acc[nt][3]) };
            *(ushort4*)&vt[b * (long)Hh * Tt + (long)h * Tt + tloc0] = pk;
        }
    }
}

// ---------- flash attention: static-max softmax, barrier-free K-loop ----------
#define LDP 56
#define LDO 68

__global__ __launch_bounds__(256) void attn(
    const unsigned short* __restrict__ qg, const unsigned short* __restrict__ kg,
    const unsigned short* __restrict__ vtg,
    float* __restrict__ po, float* __restrict__ pls)
{
    __shared__ __align__(16) char smem[49664];
    float* o_red       = (float*)smem;                      // 34816 B
    float* lred        = (float*)(smem + 34816);            // 512 B
    unsigned short* pl = (unsigned short*)(smem + 35328);   // 14336 B

    const int p    = blockIdx.x;
    const int qt   = 127 - (p >> 3);
    const int b    = p & 3;
    const int half = (p >> 2) & 1;
    const int tid  = (b << 7) | qt;
    const long qrow0 = (long)b * Tt + qt * 32;
    const int nkt = qt + 1;
    const int n0  = (nkt + 1) >> 1;
    const int cnt = half ? (nkt - n0) : n0;
    const int ust = half ? n0 : 0;

    const int t = threadIdx.x, w = t >> 6, lane = t & 63;
    const int col = lane & 15, quad = lane >> 4;
    const int plbase = w * 32 * LDP;

    bf16x8 qf[2][2];
#pragma unroll
    for (int mt = 0; mt < 2; ++mt)
#pragma unroll
        for (int kc = 0; kc < 2; ++kc)
            qf[mt][kc] = *(const bf16x8*)&qg[(qrow0 + mt * 16 + col) * Hh + kc * 32 + quad * 8];

    f32x4 oacc[2][4];
#pragma unroll
    for (int mt = 0; mt < 2; ++mt)
#pragma unroll
        for (int nt = 0; nt < 4; ++nt) oacc[mt][nt] = (f32x4){0.f, 0.f, 0.f, 0.f};
    float lsum[2][4] = {{0.f,0.f,0.f,0.f},{0.f,0.f,0.f,0.f}};

    for (int iu = w; iu < cnt; iu += 4) {
        const int u = ust + iu;
        const long krow0 = (long)b * Tt + u * 32;
        bf16x8 kf[2][2];
#pragma unroll
        for (int nt = 0; nt < 2; ++nt)
#pragma unroll
            for (int kc = 0; kc < 2; ++kc)
                kf[nt][kc] = *(const bf16x8*)&kg[(krow0 + nt * 16 + col) * Hh + kc * 32 + quad * 8];
        f32x4 s[2][2];
#pragma unroll
        for (int mt = 0; mt < 2; ++mt)
#pragma unroll
            for (int nt = 0; nt < 2; ++nt) {
                s[mt][nt] = (f32x4){0.f, 0.f, 0.f, 0.f};
#pragma unroll
                for (int kc = 0; kc < 2; ++kc)
                    s[mt][nt] = __builtin_amdgcn_mfma_f32_16x16x32_bf16(qf[mt][kc], kf[nt][kc], s[mt][nt], 0, 0, 0);
            }
#pragma unroll
        for (int mt = 0; mt < 2; ++mt)
#pragma unroll
            for (int reg = 0; reg < 4; ++reg) {
                int rloc = mt * 16 + quad * 4 + reg;
                if (u == qt) {
                    if (col > rloc)      s[mt][0][reg] = -INFINITY;
                    if (16 + col > rloc) s[mt][1][reg] = -INFINITY;
                }
                float p0 = __expf(s[mt][0][reg]);
                float p1 = __expf(s[mt][1][reg]);
                lsum[mt][reg] += p0 + p1;
                pl[plbase + rloc * LDP + col]      = f2bf(p0);
                pl[plbase + rloc * LDP + 16 + col] = f2bf(p1);
            }
        bf16x8 af0 = *(const bf16x8*)&pl[plbase + col * LDP + quad * 8];
        bf16x8 af1 = *(const bf16x8*)&pl[plbase + (16 + col) * LDP + quad * 8];
#pragma unroll
        for (int nt = 0; nt < 4; ++nt) {
            bf16x8 vf = *(const bf16x8*)&vtg[((long)b * Hh + nt * 16 + col) * Tt + u * 32 + quad * 8];
            oacc[0][nt] = __builtin_amdgcn_mfma_f32_16x16x32_bf16(af0, vf, oacc[0][nt], 0, 0, 0);
            oacc[1][nt] = __builtin_amdgcn_mfma_f32_16x16x32_bf16(af1, vf, oacc[1][nt], 0, 0, 0);
        }
    }

#pragma unroll
    for (int mt = 0; mt < 2; ++mt)
#pragma unroll
        for (int reg = 0; reg < 4; ++reg) {
            float l = lsum[mt][reg];
            l += __shfl_xor(l, 1); l += __shfl_xor(l, 2);
            l += __shfl_xor(l, 4); l += __shfl_xor(l, 8);
            if (col == 0) lred[w * 32 + mt * 16 + quad * 4 + reg] = l;
        }
#pragma unroll
    for (int mt = 0; mt < 2; ++mt)
#pragma unroll
        for (int nt = 0; nt < 4; ++nt)
#pragma unroll
            for (int reg = 0; reg < 4; ++reg)
                o_red[(w * 32 + mt * 16 + quad * 4 + reg) * LDO + nt * 16 + col] = oacc[mt][nt][reg];
    __syncthreads();
    if (t < 32)
        pls[(tid * 2 + half) * 32 + t] = lred[t] + lred[32 + t] + lred[64 + t] + lred[96 + t];
    float* pob = po + ((long)tid * 2 + half) * 2048;
#pragma unroll
    for (int j = 0; j < 8; ++j) {
        int e = t + 256 * j, r = e >> 6, c = e & 63;
        pob[e] = o_red[r * LDO + c] + o_red[(32 + r) * LDO + c]
               + o_red[(64 + r) * LDO + c] + o_red[(96 + r) * LDO + c];
    }
}

// ---------- combine: out = (O0+O1)/(l0+l1) ----------
__global__ __launch_bounds__(256) void combine(
    const float* __restrict__ po, const float* __restrict__ pls, float* __restrict__ out)
{
    const int g = blockIdx.x;
    const long orow = (((long)(g >> 7)) * Tt + (long)(g & 127) * 32) * Hh;
    const float* p0 = po + (long)g * 2 * 2048;
    const float* p1 = p0 + 2048;
    const float* l0 = pls + g * 2 * 32;
    const float* l1 = l0 + 32;
    const int t = threadIdx.x;
#pragma unroll
    for (int j = 0; j < 8; ++j) {
        int e = t + 256 * j, r = e >> 6;
        out[orow + e] = (p0[e] + p1[e]) / (l0[r] + l1[r]);
    }
}

extern "C" void kernel_launch(void* const* d_in, const int* in_sizes, int n_in,
                              void* d_out, int out_size, void* d_ws, size_t ws_size,
                              hipStream_t stream)
{
    const float* x  = (const float*)d_in[0];
    const float* Wq = (const float*)d_in[1];
    const float* Wk = (const float*)d_in[2];
    const float* Wv = (const float*)d_in[3];
    float* outp = (float*)d_out;

    unsigned short* wt = (unsigned short*)d_ws;       // 192*1024 bf16 (384 KB)
    unsigned short* qb = wt + 196608;                 // 2 MB
    unsigned short* kb = qb + 1048576;                // 2 MB
    unsigned short* vt = kb + 1048576;                // V^T [b][h][t] (2 MB)
    float* po  = (float*)(vt + 1048576);              // [512][2][2048] (8 MB)
    float* pls = po + 2097152;                        // [512][2][32]

    wt_build<<<dim3(768), dim3(256), 0, stream>>>(Wq, Wk, Wv, wt);
    qkv_gemm<<<dim3(1024), dim3(256), 0, stream>>>(x, wt, qb, kb, vt);
    attn<<<dim3(1024), dim3(256), 0, stream>>>(qb, kb, vt, po, pls);
    combine<<<dim3(512), dim3(256), 0, stream>>>(po, pls, outp);
}

// Round 2
// 160.388 us; speedup vs baseline: 1.1209x; 1.1209x over previous
//
#include <hip/hip_runtime.h>
#include <math.h>

#define Tt 4096
#define Cc 1024
#define Hh 64

typedef __attribute__((ext_vector_type(8))) short bf16x8;
typedef __attribute__((ext_vector_type(4))) float f32x4;
typedef unsigned int u32;

__device__ inline unsigned short f2bf(float f) {
    unsigned u = __float_as_uint(f);
    u = (u + 0x7FFFu + ((u >> 16) & 1u)) >> 16;   // RNE
    return (unsigned short)u;
}

// ---------- W^T bf16 [192][1024]; kScale folded into Wq ----------
__global__ __launch_bounds__(256) void wt_build(
    const float* __restrict__ Wq, const float* __restrict__ Wk,
    const float* __restrict__ Wv, unsigned short* __restrict__ Wt)
{
    int e = blockIdx.x * 256 + threadIdx.x;   // 0..196607
    int k = e & 1023, n = e >> 10;
    float v;
    if (n < 64)       v = Wq[k * 64 + n] * 0.03125f;   // fold 1024^-0.5 into Q
    else if (n < 128) v = Wk[k * 64 + (n - 64)];
    else              v = Wv[k * 64 + (n - 128)];
    Wt[n * 1024 + k] = f2bf(v);
}

// ---------- QKV GEMM v3: A-slab-in-LDS-once, barrier-free K-loop ----------
// 512 blocks x 4 waves, 2 blocks/CU. Block tile 32M x 192N; wave owns 32M x 48N.
// Prologue: whole 32x1024 A slab fp32->bf16 into LDS (coalesced, ONE barrier).
// K-loop (16 steps, unrolled): 4 ds_read_b128 + 6 global b16x8 (W^T, L2) +
// 12 MFMA per wave-step; reg double-buffer on both; immediate offsets only.
// LDS layout: row*1024 + (elem ^ ((row&7)<<3))  -- XOR swizzle, bank-balanced.
__global__ __launch_bounds__(256, 2) void qkv_gemm(
    const float* __restrict__ x, const unsigned short* __restrict__ wt,
    unsigned short* __restrict__ qb, unsigned short* __restrict__ kb,
    unsigned short* __restrict__ vt)
{
    __shared__ unsigned short as_[32 * 1024];   // 64 KiB

    const int t = threadIdx.x, w = t >> 6, lane = t & 63;
    const int col = lane & 15, quad = lane >> 4;
    const int m0 = blockIdx.x * 32;

    // ---- stage A slab: 32 rows x 1024 K, coalesced fp32 loads, bf16 to LDS
    {
        const float* xr = x + (long)m0 * Cc;
#pragma unroll
        for (int i = 0; i < 32; ++i) {
            float4 v = *(const float4*)&xr[i * Cc + t * 4];
            ushort4 pk = { f2bf(v.x), f2bf(v.y), f2bf(v.z), f2bf(v.w) };
            int woff = (t * 4) ^ ((i & 7) << 3);       // swizzle (shorts)
            *(ushort4*)&as_[i * 1024 + woff] = pk;
        }
    }
    __syncthreads();   // the only barrier

    // ---- per-lane LDS base pointers (kc swizzle folded in)
    const unsigned short* aB[2];
#pragma unroll
    for (int kc = 0; kc < 2; ++kc)
        aB[kc] = &as_[col * 1024 + ((kc * 32 + quad * 8) ^ ((col & 7) << 3))];
    // reads: aB[kc] + mt*16*1024 + k*64   (pure immediates)

    // ---- B base pointers: wave w owns n-tiles w*3 .. w*3+2
    const unsigned short* pB[3];
#pragma unroll
    for (int nt = 0; nt < 3; ++nt)
        pB[nt] = wt + ((w * 3 + nt) * 16 + col) * 1024 + quad * 8;
    // reads: pB[nt] + k*64 + kc*32   (pure immediates)

    f32x4 acc[2][3];
#pragma unroll
    for (int mt = 0; mt < 2; ++mt)
#pragma unroll
        for (int nt = 0; nt < 3; ++nt) acc[mt][nt] = (f32x4){0.f, 0.f, 0.f, 0.f};

    bf16x8 bfr[2][3][2];   // [buf][nt][kc]
    bf16x8 afr[2][2][2];   // [buf][mt][kc]

    // prologue loads for k = 0
#pragma unroll
    for (int nt = 0; nt < 3; ++nt)
#pragma unroll
        for (int kc = 0; kc < 2; ++kc)
            bfr[0][nt][kc] = *(const bf16x8*)(pB[nt] + kc * 32);
#pragma unroll
    for (int mt = 0; mt < 2; ++mt)
#pragma unroll
        for (int kc = 0; kc < 2; ++kc)
            afr[0][mt][kc] = *(const bf16x8*)(aB[kc] + mt * 16 * 1024);

#pragma unroll
    for (int k = 0; k < 16; ++k) {
        const int cur = k & 1, nxt = cur ^ 1;
        if (k < 15) {
            const int ko = (k + 1) * 64;
#pragma unroll
            for (int nt = 0; nt < 3; ++nt)
#pragma unroll
                for (int kc = 0; kc < 2; ++kc)
                    bfr[nxt][nt][kc] = *(const bf16x8*)(pB[nt] + ko + kc * 32);
#pragma unroll
            for (int mt = 0; mt < 2; ++mt)
#pragma unroll
                for (int kc = 0; kc < 2; ++kc)
                    afr[nxt][mt][kc] = *(const bf16x8*)(aB[kc] + mt * 16 * 1024 + ko);
        }
#pragma unroll
        for (int kc = 0; kc < 2; ++kc)
#pragma unroll
            for (int nt = 0; nt < 3; ++nt)
#pragma unroll
                for (int mt = 0; mt < 2; ++mt)
                    acc[mt][nt] = __builtin_amdgcn_mfma_f32_16x16x32_bf16(
                        afr[cur][mt][kc], bfr[cur][nt][kc], acc[mt][nt], 0, 0, 0);
    }

    // ---- epilogue: wave w -> n-tiles ntg = 3w..3w+2, rows m0 + mt*16 + quad*4 + reg
    const long bidx = m0 >> 12;
    const int tbase = m0 & 4095;
#pragma unroll
    for (int mt = 0; mt < 2; ++mt)
#pragma unroll
        for (int nt = 0; nt < 3; ++nt) {
            int ntg = w * 3 + nt;
            int n = ntg * 16 + col;
            int row = m0 + mt * 16 + quad * 4;
            if (ntg < 4) {
#pragma unroll
                for (int reg = 0; reg < 4; ++reg)
                    qb[(long)(row + reg) * Hh + n] = f2bf(acc[mt][nt][reg]);
            } else if (ntg < 8) {
#pragma unroll
                for (int reg = 0; reg < 4; ++reg)
                    kb[(long)(row + reg) * Hh + (n - 64)] = f2bf(acc[mt][nt][reg]);
            } else {
                int h = n - 128;
                ushort4 pk = { f2bf(acc[mt][nt][0]), f2bf(acc[mt][nt][1]),
                               f2bf(acc[mt][nt][2]), f2bf(acc[mt][nt][3]) };
                *(ushort4*)&vt[(bidx * Hh + h) * (long)Tt + tbase + mt * 16 + quad * 4] = pk;
            }
        }
}

// ---------- flash attention: static-max softmax, barrier-free K-loop ----------
#define LDP 56
#define LDO 68

__global__ __launch_bounds__(256) void attn(
    const unsigned short* __restrict__ qg, const unsigned short* __restrict__ kg,
    const unsigned short* __restrict__ vtg,
    float* __restrict__ po, float* __restrict__ pls)
{
    __shared__ __align__(16) char smem[49664];
    float* o_red       = (float*)smem;                      // 34816 B
    float* lred        = (float*)(smem + 34816);            // 512 B
    unsigned short* pl = (unsigned short*)(smem + 35328);   // 14336 B

    const int p    = blockIdx.x;
    const int qt   = 127 - (p >> 3);
    const int b    = p & 3;
    const int half = (p >> 2) & 1;
    const int tid  = (b << 7) | qt;
    const long qrow0 = (long)b * Tt + qt * 32;
    const int nkt = qt + 1;
    const int n0  = (nkt + 1) >> 1;
    const int cnt = half ? (nkt - n0) : n0;
    const int ust = half ? n0 : 0;

    const int t = threadIdx.x, w = t >> 6, lane = t & 63;
    const int col = lane & 15, quad = lane >> 4;
    const int plbase = w * 32 * LDP;

    bf16x8 qf[2][2];
#pragma unroll
    for (int mt = 0; mt < 2; ++mt)
#pragma unroll
        for (int kc = 0; kc < 2; ++kc)
            qf[mt][kc] = *(const bf16x8*)&qg[(qrow0 + mt * 16 + col) * Hh + kc * 32 + quad * 8];

    f32x4 oacc[2][4];
#pragma unroll
    for (int mt = 0; mt < 2; ++mt)
#pragma unroll
        for (int nt = 0; nt < 4; ++nt) oacc[mt][nt] = (f32x4){0.f, 0.f, 0.f, 0.f};
    float lsum[2][4] = {{0.f,0.f,0.f,0.f},{0.f,0.f,0.f,0.f}};

    for (int iu = w; iu < cnt; iu += 4) {
        const int u = ust + iu;
        const long krow0 = (long)b * Tt + u * 32;
        bf16x8 kf[2][2];
#pragma unroll
        for (int nt = 0; nt < 2; ++nt)
#pragma unroll
            for (int kc = 0; kc < 2; ++kc)
                kf[nt][kc] = *(const bf16x8*)&kg[(krow0 + nt * 16 + col) * Hh + kc * 32 + quad * 8];
        f32x4 s[2][2];
#pragma unroll
        for (int mt = 0; mt < 2; ++mt)
#pragma unroll
            for (int nt = 0; nt < 2; ++nt) {
                s[mt][nt] = (f32x4){0.f, 0.f, 0.f, 0.f};
#pragma unroll
                for (int kc = 0; kc < 2; ++kc)
                    s[mt][nt] = __builtin_amdgcn_mfma_f32_16x16x32_bf16(qf[mt][kc], kf[nt][kc], s[mt][nt], 0, 0, 0);
            }
#pragma unroll
        for (int mt = 0; mt < 2; ++mt)
#pragma unroll
            for (int reg = 0; reg < 4; ++reg) {
                int rloc = mt * 16 + quad * 4 + reg;
                if (u == qt) {
                    if (col > rloc)      s[mt][0][reg] = -INFINITY;
                    if (16 + col > rloc) s[mt][1][reg] = -INFINITY;
                }
                float p0 = __expf(s[mt][0][reg]);
                float p1 = __expf(s[mt][1][reg]);
                lsum[mt][reg] += p0 + p1;
                pl[plbase + rloc * LDP + col]      = f2bf(p0);
                pl[plbase + rloc * LDP + 16 + col] = f2bf(p1);
            }
        bf16x8 af0 = *(const bf16x8*)&pl[plbase + col * LDP + quad * 8];
        bf16x8 af1 = *(const bf16x8*)&pl[plbase + (16 + col) * LDP + quad * 8];
#pragma unroll
        for (int nt = 0; nt < 4; ++nt) {
            bf16x8 vf = *(const bf16x8*)&vtg[((long)b * Hh + nt * 16 + col) * Tt + u * 32 + quad * 8];
            oacc[0][nt] = __builtin_amdgcn_mfma_f32_16x16x32_bf16(af0, vf, oacc[0][nt], 0, 0, 0);
            oacc[1][nt] = __builtin_amdgcn_mfma_f32_16x16x32_bf16(af1, vf, oacc[1][nt], 0, 0, 0);
        }
    }

#pragma unroll
    for (int mt = 0; mt < 2; ++mt)
#pragma unroll
        for (int reg = 0; reg < 4; ++reg) {
            float l = lsum[mt][reg];
            l += __shfl_xor(l, 1); l += __shfl_xor(l, 2);
            l += __shfl_xor(l, 4); l += __shfl_xor(l, 8);
            if (col == 0) lred[w * 32 + mt * 16 + quad * 4 + reg] = l;
        }
#pragma unroll
    for (int mt = 0; mt < 2; ++mt)
#pragma unroll
        for (int nt = 0; nt < 4; ++nt)
#pragma unroll
            for (int reg = 0; reg < 4; ++reg)
                o_red[(w * 32 + mt * 16 + quad * 4 + reg) * LDO + nt * 16 + col] = oacc[mt][nt][reg];
    __syncthreads();
    if (t < 32)
        pls[(tid * 2 + half) * 32 + t] = lred[t] + lred[32 + t] + lred[64 + t] + lred[96 + t];
    float* pob = po + ((long)tid * 2 + half) * 2048;
#pragma unroll
    for (int j = 0; j < 8; ++j) {
        int e = t + 256 * j, r = e >> 6, c = e & 63;
        pob[e] = o_red[r * LDO + c] + o_red[(32 + r) * LDO + c]
               + o_red[(64 + r) * LDO + c] + o_red[(96 + r) * LDO + c];
    }
}

// ---------- combine: out = (O0+O1)/(l0+l1) ----------
__global__ __launch_bounds__(256) void combine(
    const float* __restrict__ po, const float* __restrict__ pls, float* __restrict__ out)
{
    const int g = blockIdx.x;
    const long orow = (((long)(g >> 7)) * Tt + (long)(g & 127) * 32) * Hh;
    const float* p0 = po + (long)g * 2 * 2048;
    const float* p1 = p0 + 2048;
    const float* l0 = pls + g * 2 * 32;
    const float* l1 = l0 + 32;
    const int t = threadIdx.x;
#pragma unroll
    for (int j = 0; j < 8; ++j) {
        int e = t + 256 * j, r = e >> 6;
        out[orow + e] = (p0[e] + p1[e]) / (l0[r] + l1[r]);
    }
}

extern "C" void kernel_launch(void* const* d_in, const int* in_sizes, int n_in,
                              void* d_out, int out_size, void* d_ws, size_t ws_size,
                              hipStream_t stream)
{
    const float* x  = (const float*)d_in[0];
    const float* Wq = (const float*)d_in[1];
    const float* Wk = (const float*)d_in[2];
    const float* Wv = (const float*)d_in[3];
    float* outp = (float*)d_out;

    unsigned short* wt = (unsigned short*)d_ws;       // 192*1024 bf16 (384 KB)
    unsigned short* qb = wt + 196608;                 // 2 MB
    unsigned short* kb = qb + 1048576;                // 2 MB
    unsigned short* vt = kb + 1048576;                // V^T [b][h][t] (2 MB)
    float* po  = (float*)(vt + 1048576);              // [512][2][2048] (8 MB)
    float* pls = po + 2097152;                        // [512][2][32]

    wt_build<<<dim3(768), dim3(256), 0, stream>>>(Wq, Wk, Wv, wt);
    qkv_gemm<<<dim3(512), dim3(256), 0, stream>>>(x, wt, qb, kb, vt);
    attn<<<dim3(1024), dim3(256), 0, stream>>>(qb, kb, vt, po, pls);
    combine<<<dim3(512), dim3(256), 0, stream>>>(po, pls, outp);
}